// Round 8
// baseline (236.567 us; speedup 1.0000x reference)
//
#include <hip/hip_runtime.h>

#define THRESH 0.7f

typedef float nfloat2 __attribute__((ext_vector_type(2)));
typedef float nfloat4 __attribute__((ext_vector_type(4)));

__device__ __forceinline__ float4 nt_load4(const float4* p) {
    nfloat4 v = __builtin_nontemporal_load(reinterpret_cast<const nfloat4*>(p));
    return make_float4(v.x, v.y, v.z, v.w);
}

__device__ __forceinline__ float2 nt_load2(const float2* p) {
    nfloat2 v = __builtin_nontemporal_load(reinterpret_cast<const nfloat2*>(p));
    return make_float2(v.x, v.y);
}

__device__ __forceinline__ float4 proc_one(float4 r, float4 d, float keep,
                                           float fw, float fh) {
    float w = r.z - r.x;
    float h = r.w - r.y;
    float nx1 = fminf(fmaxf(fmaf(d.x, w, r.x), 0.0f), fw);
    float ny1 = fminf(fmaxf(fmaf(d.y, h, r.y), 0.0f), fh);
    float nx2 = fminf(fmaxf(fmaf(d.z, w, r.z), 0.0f), fw);
    float ny2 = fminf(fmaxf(fmaf(d.w, h, r.w), 0.0f), fh);
    return make_float4(nx1 * keep, ny1 * keep, nx2 * keep, ny2 * keep);
}

// Round 7 (nt-loads, scalar) broke the L3-churn plateau: 80 -> <59 us.
// Reads now stream from HBM with full miss latency, so MLP matters again:
// this round layers the round-2 vec4 structure (10 independent 16B nt-loads
// in flight per lane) on top. Stores stay cached (L3 now exclusively holds
// the 100.7 MB write stream; nt-stores measured 2x write amplification r1).
__global__ __launch_bounds__(256) void rnet_post_nt4(
    const float4* __restrict__ cls4,        // [M/2] two (bg,face) pairs per float4
    const float4* __restrict__ reg,         // [M]
    const float4* __restrict__ rects,       // [M]
    const int*    __restrict__ hptr,
    const int*    __restrict__ wptr,
    float4* __restrict__ out_rects,         // [M]
    float4* __restrict__ out_scores4,       // [M/4]
    float4* __restrict__ out_keep4,         // [M/4]
    int M4)                                 // M/4
{
    int i = blockIdx.x * blockDim.x + threadIdx.x;
    if (i >= M4) return;

    const float fh = (float)*hptr;
    const float fw = (float)*wptr;

    long b = 4l * i;
    // 10 independent nt dwordx4 loads issued back-to-back.
    float4 c01 = nt_load4(&cls4[2l * i]);
    float4 c23 = nt_load4(&cls4[2l * i + 1]);
    float4 r0 = nt_load4(&rects[b + 0]);
    float4 r1 = nt_load4(&rects[b + 1]);
    float4 r2 = nt_load4(&rects[b + 2]);
    float4 r3 = nt_load4(&rects[b + 3]);
    float4 d0 = nt_load4(&reg[b + 0]);
    float4 d1 = nt_load4(&reg[b + 1]);
    float4 d2 = nt_load4(&reg[b + 2]);
    float4 d3 = nt_load4(&reg[b + 3]);

    float s0 = c01.y, s1 = c01.w, s2 = c23.y, s3 = c23.w;
    float k0 = (s0 > THRESH) ? 1.0f : 0.0f;
    float k1 = (s1 > THRESH) ? 1.0f : 0.0f;
    float k2 = (s2 > THRESH) ? 1.0f : 0.0f;
    float k3 = (s3 > THRESH) ? 1.0f : 0.0f;

    float4 o0 = proc_one(r0, d0, k0, fw, fh);
    float4 o1 = proc_one(r1, d1, k1, fw, fh);
    float4 o2 = proc_one(r2, d2, k2, fw, fh);
    float4 o3 = proc_one(r3, d3, k3, fw, fh);

    out_rects[b + 0] = o0;
    out_rects[b + 1] = o1;
    out_rects[b + 2] = o2;
    out_rects[b + 3] = o3;
    out_scores4[i] = make_float4(s0 * k0, s1 * k1, s2 * k2, s3 * k3);
    out_keep4[i]   = make_float4(k0, k1, k2, k3);
}

// Scalar nt fallback (only used when M % 4 != 0) — round-7 kernel.
__global__ __launch_bounds__(256) void rnet_post_ntload(
    const float2* __restrict__ cls,
    const float4* __restrict__ reg,
    const float4* __restrict__ rects,
    const int*    __restrict__ hptr,
    const int*    __restrict__ wptr,
    float4* __restrict__ out_rects,
    float*  __restrict__ out_scores,
    float*  __restrict__ out_keep,
    int M)
{
    int i = blockIdx.x * blockDim.x + threadIdx.x;
    if (i >= M) return;

    const float fh = (float)*hptr;
    const float fw = (float)*wptr;

    float2 c = nt_load2(&cls[i]);
    float score = c.y;
    float keep = (score > THRESH) ? 1.0f : 0.0f;

    float4 o = proc_one(nt_load4(&rects[i]), nt_load4(&reg[i]), keep, fw, fh);
    out_rects[i]  = o;
    out_scores[i] = score * keep;
    out_keep[i]   = keep;
}

extern "C" void kernel_launch(void* const* d_in, const int* in_sizes, int n_in,
                              void* d_out, int out_size, void* d_ws, size_t ws_size,
                              hipStream_t stream) {
    const float*  clsf  = (const float*)d_in[0];   // classifier [B,N,2]
    const float4* reg   = (const float4*)d_in[1];  // bbox_regress [B,N,4]
    const float4* rects = (const float4*)d_in[2];  // input_rects [B,N,4]
    const int*    hptr  = (const int*)d_in[3];     // input_height scalar
    const int*    wptr  = (const int*)d_in[4];     // input_width scalar

    const int M = in_sizes[0] / 2;  // B*N

    float* out = (float*)d_out;
    float4* out_rects  = (float4*)out;        // 4*M floats
    float*  out_scores = out + 4ll * M;       // M floats
    float*  out_keep   = out + 5ll * M;       // M floats

    const int block = 256;

    if ((M & 3) == 0) {
        const int M4 = M >> 2;
        const int grid = (M4 + block - 1) / block;
        rnet_post_nt4<<<grid, block, 0, stream>>>(
            (const float4*)clsf, reg, rects, hptr, wptr,
            out_rects, (float4*)out_scores, (float4*)out_keep, M4);
    } else {
        const int grid = (M + block - 1) / block;
        rnet_post_ntload<<<grid, block, 0, stream>>>(
            (const float2*)clsf, reg, rects, hptr, wptr,
            out_rects, out_scores, out_keep, M);
    }
}

// Round 9
// 214.179 us; speedup vs baseline: 1.1045x; 1.1045x over previous
//
#include <hip/hip_runtime.h>

#define THRESH 0.7f

typedef float nfloat2 __attribute__((ext_vector_type(2)));
typedef float nfloat4 __attribute__((ext_vector_type(4)));

__device__ __forceinline__ float2 nt_load2(const float2* p) {
    nfloat2 v = __builtin_nontemporal_load(reinterpret_cast<const nfloat2*>(p));
    return make_float2(v.x, v.y);
}

__device__ __forceinline__ float4 nt_load4(const float4* p) {
    nfloat4 v = __builtin_nontemporal_load(reinterpret_cast<const nfloat4*>(p));
    return make_float4(v.x, v.y, v.z, v.w);
}

// Best structure = round 7: scalar 1-elem/lane, nt loads (bypass L3 so the
// 100.7 MB write stream owns the Infinity Cache; broke the 80 us churn
// plateau to <59 us). This round adds keep-predicated reg/rects loads:
// with nt loads an exec-masked lane issues NO request, so ~24% of reg/rects
// 64B lines (all 4 elems non-kept, 0.7^4) are never fetched (~32 MB saved).
// vec4+nt regressed (r8: 71 us — 64B-stride-per-lane breaks nt coalescing);
// nt stores regressed (r1: 2x write amplification). Keep scalar + cached
// stores.
__global__ __launch_bounds__(256) void rnet_post_ntp(
    const float2* __restrict__ cls,    // [M] pairs: (bg, face) score
    const float4* __restrict__ reg,    // [M] dx1,dy1,dx2,dy2
    const float4* __restrict__ rects,  // [M] x1,y1,x2,y2
    const int*    __restrict__ hptr,
    const int*    __restrict__ wptr,
    float4* __restrict__ out_rects,    // [M]
    float*  __restrict__ out_scores,   // [M]
    float*  __restrict__ out_keep,     // [M]
    int M)
{
    int i = blockIdx.x * blockDim.x + threadIdx.x;
    if (i >= M) return;

    const float fh = (float)*hptr;
    const float fw = (float)*wptr;

    float2 c = nt_load2(&cls[i]);
    float score = c.y;
    bool k = score > THRESH;

    float4 o = make_float4(0.0f, 0.0f, 0.0f, 0.0f);
    float s = 0.0f;
    float kf = 0.0f;

    if (k) {  // exec-masked: non-kept lanes issue no reg/rects requests
        float4 r = nt_load4(&rects[i]);
        float4 d = nt_load4(&reg[i]);
        float w = r.z - r.x;
        float h = r.w - r.y;
        o.x = fminf(fmaxf(fmaf(d.x, w, r.x), 0.0f), fw);
        o.y = fminf(fmaxf(fmaf(d.y, h, r.y), 0.0f), fh);
        o.z = fminf(fmaxf(fmaf(d.z, w, r.z), 0.0f), fw);
        o.w = fminf(fmaxf(fmaf(d.w, h, r.w), 0.0f), fh);
        s = score;
        kf = 1.0f;
    }

    out_rects[i]  = o;
    out_scores[i] = s;
    out_keep[i]   = kf;
}

extern "C" void kernel_launch(void* const* d_in, const int* in_sizes, int n_in,
                              void* d_out, int out_size, void* d_ws, size_t ws_size,
                              hipStream_t stream) {
    const float2* cls   = (const float2*)d_in[0];  // classifier [B,N,2]
    const float4* reg   = (const float4*)d_in[1];  // bbox_regress [B,N,4]
    const float4* rects = (const float4*)d_in[2];  // input_rects [B,N,4]
    const int*    hptr  = (const int*)d_in[3];     // input_height scalar
    const int*    wptr  = (const int*)d_in[4];     // input_width scalar

    const int M = in_sizes[0] / 2;  // B*N

    float* out = (float*)d_out;
    float4* out_rects  = (float4*)out;        // 4*M floats
    float*  out_scores = out + 4ll * M;       // M floats
    float*  out_keep   = out + 5ll * M;       // M floats

    const int block = 256;
    const int grid = (M + block - 1) / block;
    rnet_post_ntp<<<grid, block, 0, stream>>>(cls, reg, rects, hptr, wptr,
                                              out_rects, out_scores, out_keep, M);
}